// Round 1
// baseline (5367.264 us; speedup 1.0000x reference)
//
#include <hip/hip_runtime.h>

// 2-layer GRU (TF GRUCell semantics) + final dense, fp32 persistent kernel.
// B=4096, T=64, F=32, U1=256, U2=128.
// One block = 16 batches for the entire T loop; h-state lives in LDS.

constexpr int Bc  = 4096;
constexpr int Tc  = 64;
constexpr int Fc  = 32;
constexpr int U1c = 256;
constexpr int U2c = 128;
constexpr int D1  = Fc + U1c;    // 288
constexpr int D2  = U1c + U2c;   // 384
constexpr int NB  = 16;          // batches per block
constexpr int NTHR = 512;
constexpr int XC1_LD = D1 + 4;   // 292 (keeps float4 alignment, 1168B rows)
constexpr int XC2_LD = D2 + 4;   // 388 (1552B rows)

__device__ __forceinline__ float sigmoidf_(float x) {
  return 1.0f / (1.0f + __expf(-x));
}
__device__ __forceinline__ float tanhf_(float x) {
  x = fminf(fmaxf(x, -15.0f), 15.0f);
  const float s = __expf(2.0f * x);
  return (s - 1.0f) / (s + 1.0f);
}

__global__ __launch_bounds__(NTHR, 1)
void gru_persist(const float* __restrict__ frames,
                 const float* __restrict__ W1g, const float* __restrict__ b1g,
                 const float* __restrict__ W1c, const float* __restrict__ b1c,
                 const float* __restrict__ W2g, const float* __restrict__ b2g,
                 const float* __restrict__ W2c, const float* __restrict__ b2c,
                 const float* __restrict__ Wd,  const float* __restrict__ bd,
                 float* __restrict__ out)
{
  __shared__ float xc1[NB][XC1_LD];   // [x_t | h1 (or r1*h1)]
  __shared__ float xc2[NB][XC2_LD];   // [h1_new | h2 (or r2*h2)]
  __shared__ float h2s[NB][U2c];      // h2 state (kept clean through the step)
  __shared__ float u2s[NB][U2c];      // staged u2 gate

  const int tid = threadIdx.x;
  const int tt  = tid & 255;      // column owner (0..255)
  const int g   = tid >> 8;       // batch half (0/1)
  const int b0g = g * 8;
  const int b0  = blockIdx.x * NB;

  const int c2c = tid & 127;      // cand2 column
  const int q   = tid >> 7;       // cand2 batch quarter (0..3)

  // biases preloaded to registers
  const float br1 = b1g[tt];
  const float bu1 = b1g[256 + tt];
  const float bc1 = b1c[tt];
  const float bg2 = b2g[tt];
  const float bc2 = b2c[c2c];

  // zero-init state
  for (int i = tid; i < NB * XC1_LD; i += NTHR) (&xc1[0][0])[i] = 0.0f;
  for (int i = tid; i < NB * XC2_LD; i += NTHR) (&xc2[0][0])[i] = 0.0f;
  for (int i = tid; i < NB * U2c; i += NTHR) { (&h2s[0][0])[i] = 0.0f; (&u2s[0][0])[i] = 0.0f; }
  __syncthreads();

  const int xb = tid >> 5;   // 0..15
  const int xf = tid & 31;

  for (int t = 0; t < Tc; ++t) {
    // ---- load x_t (one float per thread, coalesced) ----
    xc1[xb][xf] = frames[(size_t)(b0 + xb) * (Tc * Fc) + t * Fc + xf];
    __syncthreads();

    // ---- layer1 gates: cols tt (r) and tt+256 (u), 8 batches ----
    float accR[8], accU[8];
#pragma unroll
    for (int b = 0; b < 8; ++b) { accR[b] = br1; accU[b] = bu1; }
    {
      const float* wp = W1g + tt;
      for (int k = 0; k < D1; k += 4, wp += 4 * 512) {
        const float wr0 = wp[0],    wu0 = wp[256];
        const float wr1 = wp[512],  wu1 = wp[768];
        const float wr2 = wp[1024], wu2 = wp[1280];
        const float wr3 = wp[1536], wu3 = wp[1792];
#pragma unroll
        for (int b = 0; b < 8; ++b) {
          const float4 xv = *(const float4*)&xc1[b0g + b][k];
          accR[b] = fmaf(xv.x, wr0, accR[b]);
          accR[b] = fmaf(xv.y, wr1, accR[b]);
          accR[b] = fmaf(xv.z, wr2, accR[b]);
          accR[b] = fmaf(xv.w, wr3, accR[b]);
          accU[b] = fmaf(xv.x, wu0, accU[b]);
          accU[b] = fmaf(xv.y, wu1, accU[b]);
          accU[b] = fmaf(xv.z, wu2, accU[b]);
          accU[b] = fmaf(xv.w, wu3, accU[b]);
        }
      }
    }
    float hold[8], u1[8];
#pragma unroll
    for (int b = 0; b < 8; ++b) {
      hold[b] = xc1[b0g + b][Fc + tt];   // h1_old (own column)
      u1[b]   = sigmoidf_(accU[b]);
    }
    __syncthreads();   // all gates1 reads of xc1 complete
#pragma unroll
    for (int b = 0; b < 8; ++b) {
      const float r = sigmoidf_(accR[b]);
      xc1[b0g + b][Fc + tt] = r * hold[b];     // overwrite h1 region with r*h1
    }
    __syncthreads();

    // ---- layer1 candidate: col tt ----
    float accC[8];
#pragma unroll
    for (int b = 0; b < 8; ++b) accC[b] = bc1;
    {
      const float* wp = W1c + tt;
      for (int k = 0; k < D1; k += 4, wp += 4 * 256) {
        const float w0 = wp[0], w1 = wp[256], w2 = wp[512], w3 = wp[768];
#pragma unroll
        for (int b = 0; b < 8; ++b) {
          const float4 xv = *(const float4*)&xc1[b0g + b][k];
          accC[b] = fmaf(xv.x, w0, accC[b]);
          accC[b] = fmaf(xv.y, w1, accC[b]);
          accC[b] = fmaf(xv.z, w2, accC[b]);
          accC[b] = fmaf(xv.w, w3, accC[b]);
        }
      }
    }
    float h1n[8];
#pragma unroll
    for (int b = 0; b < 8; ++b) {
      const float c = tanhf_(accC[b]);
      h1n[b] = c + u1[b] * (hold[b] - c);
    }
    __syncthreads();   // cand1 reads done
#pragma unroll
    for (int b = 0; b < 8; ++b) {
      xc1[b0g + b][Fc + tt] = h1n[b];   // h1 state for next step
      xc2[b0g + b][tt]      = h1n[b];   // layer2 input
    }
    __syncthreads();

    // ---- layer2 gates: col tt (r2 for tt<128, u2 for tt>=128) ----
    float acc2[8];
#pragma unroll
    for (int b = 0; b < 8; ++b) acc2[b] = bg2;
    {
      const float* wp = W2g + tt;
      for (int k = 0; k < D2; k += 4, wp += 4 * 256) {
        const float w0 = wp[0], w1 = wp[256], w2 = wp[512], w3 = wp[768];
#pragma unroll
        for (int b = 0; b < 8; ++b) {
          const float4 xv = *(const float4*)&xc2[b0g + b][k];
          acc2[b] = fmaf(xv.x, w0, acc2[b]);
          acc2[b] = fmaf(xv.y, w1, acc2[b]);
          acc2[b] = fmaf(xv.z, w2, acc2[b]);
          acc2[b] = fmaf(xv.w, w3, acc2[b]);
        }
      }
    }
    float r2[8];
    if (tt >= 128) {
#pragma unroll
      for (int b = 0; b < 8; ++b) u2s[b0g + b][tt - 128] = sigmoidf_(acc2[b]);
    } else {
#pragma unroll
      for (int b = 0; b < 8; ++b) r2[b] = sigmoidf_(acc2[b]);
    }
    __syncthreads();   // gates2 reads done + u2s visible
    if (tt < 128) {
#pragma unroll
      for (int b = 0; b < 8; ++b)
        xc2[b0g + b][U1c + tt] = r2[b] * h2s[b0g + b][tt];
    }
    __syncthreads();

    // ---- layer2 candidate: col c2c, 4 batches (quarter q) ----
    float accC2[4];
#pragma unroll
    for (int b = 0; b < 4; ++b) accC2[b] = bc2;
    {
      const float* wp = W2c + c2c;
      const int bq = q * 4;
      for (int k = 0; k < D2; k += 4, wp += 4 * 128) {
        const float w0 = wp[0], w1 = wp[128], w2 = wp[256], w3 = wp[384];
#pragma unroll
        for (int b = 0; b < 4; ++b) {
          const float4 xv = *(const float4*)&xc2[bq + b][k];
          accC2[b] = fmaf(xv.x, w0, accC2[b]);
          accC2[b] = fmaf(xv.y, w1, accC2[b]);
          accC2[b] = fmaf(xv.z, w2, accC2[b]);
          accC2[b] = fmaf(xv.w, w3, accC2[b]);
        }
      }
    }
    __syncthreads();   // cand2 reads done before overwriting xc2 h2-region
    {
      const int bq = q * 4;
#pragma unroll
      for (int b = 0; b < 4; ++b) {
        const float c    = tanhf_(accC2[b]);
        const float hOld = h2s[bq + b][c2c];
        const float u    = u2s[bq + b][c2c];
        const float hn   = c + u * (hOld - c);
        h2s[bq + b][c2c]       = hn;
        xc2[bq + b][U1c + c2c] = hn;   // h2 state for next step's gates2
      }
    }
    __syncthreads();
  }

  // ---- final dense: out[b][o] = bd[o] + h2[b] . Wd[:,o] ----
  {
    const int o = tid & 31;
    const int b = tid >> 5;   // 0..15
    float acc = bd[o];
    for (int c = 0; c < U2c; ++c)
      acc = fmaf(h2s[b][c], Wd[c * 32 + o], acc);
    out[(size_t)(b0 + b) * Fc + o] = acc;
  }
}

extern "C" void kernel_launch(void* const* d_in, const int* in_sizes, int n_in,
                              void* d_out, int out_size, void* d_ws, size_t ws_size,
                              hipStream_t stream) {
  const float* frames = (const float*)d_in[0];
  const float* W1g = (const float*)d_in[1];
  const float* b1g = (const float*)d_in[2];
  const float* W1c = (const float*)d_in[3];
  const float* b1c = (const float*)d_in[4];
  const float* W2g = (const float*)d_in[5];
  const float* b2g = (const float*)d_in[6];
  const float* W2c = (const float*)d_in[7];
  const float* b2c = (const float*)d_in[8];
  const float* Wd  = (const float*)d_in[9];
  const float* bd  = (const float*)d_in[10];
  float* outp = (float*)d_out;

  hipLaunchKernelGGL(gru_persist, dim3(Bc / NB), dim3(NTHR), 0, stream,
                     frames, W1g, b1g, W1c, b1c, W2g, b2g, W2c, b2c, Wd, bd, outp);
}

// Round 2
// 4745.060 us; speedup vs baseline: 1.1311x; 1.1311x over previous
//
#include <hip/hip_runtime.h>

// 2-layer GRU (TF GRUCell) + dense, via bf16x3 split-precision MFMA.
// B=4096, T=64, F=32, U1=256, U2=128. fp32-equivalent accuracy:
// A = Ahi+Alo (bf16), W = Whi+Wlo (bf16); A*W ~= AhiWhi + AloWhi + AhiWlo
// (dropped AloWlo ~ 2^-18 relative). All accumulation fp32 in MFMA.
// One block = 16 batches (one MFMA M-tile) for the whole T loop.
// Gate/u/h_old state carried in REGISTERS (wave owns same cols in gate and
// candidate matmuls) -> LDS is only the two A-operand panels (44 KB).

typedef unsigned short u16;
typedef __attribute__((ext_vector_type(8))) short bhalf8;   // 8 bf16 (4 VGPRs)
typedef __attribute__((ext_vector_type(4))) float fx4;

constexpr int Bc = 4096, Tc = 64, Fc = 32, U1 = 256, U2 = 128;
constexpr int K1 = Fc + U1;   // 288
constexpr int K2 = U1 + U2;   // 384
constexpr int NB = 16, NTHR = 512;
constexpr int LD1 = K1 + 8;   // 296 u16: 592B rows, 16B aligned, ~2-way banks
constexpr int LD2 = K2 + 8;   // 392 u16: 784B rows

// d_ws layout (u16 element offsets): transposed bf16 weights, hi then lo.
constexpr int nW1g = K1 * 512, nW1c = K1 * 256, nW2g = K2 * 256, nW2c = K2 * 128;
constexpr int oW1g_h = 0;
constexpr int oW1g_l = oW1g_h + nW1g;
constexpr int oW1c_h = oW1g_l + nW1g;
constexpr int oW1c_l = oW1c_h + nW1c;
constexpr int oW2g_h = oW1c_l + nW1c;
constexpr int oW2g_l = oW2g_h + nW2g;
constexpr int oW2c_h = oW2g_l + nW2g;
constexpr int oW2c_l = oW2c_h + nW2c;
constexpr int WTOT   = oW2c_l + nW2c;   // 737280 u16 = 1.47 MB

__device__ __forceinline__ u16 bf16_rne(float x) {
  unsigned u = __float_as_uint(x);
  return (u16)((u + 0x7fffu + ((u >> 16) & 1u)) >> 16);
}
__device__ __forceinline__ float bf16_f(u16 h) {
  return __uint_as_float(((unsigned)h) << 16);
}
__device__ __forceinline__ float sigm(float x) { return 1.0f / (1.0f + __expf(-x)); }
__device__ __forceinline__ float tanh_(float x) {
  x = fminf(fmaxf(x, -15.0f), 15.0f);
  const float s = __expf(2.0f * x);
  return (s - 1.0f) / (s + 1.0f);
}

// ---- prep: W[K][N] fp32 -> WT_hi[N][K], WT_lo[N][K] bf16 (u16) ----
__global__ void prep_weights(const float* __restrict__ W1g, const float* __restrict__ W1c,
                             const float* __restrict__ W2g, const float* __restrict__ W2c,
                             u16* __restrict__ ws) {
  int j = blockIdx.x * 256 + threadIdx.x;
  if (j >= WTOT / 2) return;
  const float* src; u16 *dh, *dl; int K, N, jj;
  if (j < nW1g)                    { src = W1g; K = K1; N = 512; jj = j;                    dh = ws + oW1g_h; dl = ws + oW1g_l; }
  else if (j < nW1g + nW1c)        { src = W1c; K = K1; N = 256; jj = j - nW1g;             dh = ws + oW1c_h; dl = ws + oW1c_l; }
  else if (j < nW1g + nW1c + nW2g) { src = W2g; K = K2; N = 256; jj = j - nW1g - nW1c;      dh = ws + oW2g_h; dl = ws + oW2g_l; }
  else                             { src = W2c; K = K2; N = 128; jj = j - nW1g - nW1c - nW2g; dh = ws + oW2c_h; dl = ws + oW2c_l; }
  int n = jj / K, k = jj - n * K;
  float v = src[(size_t)k * N + n];
  u16 h = bf16_rne(v);
  dh[(size_t)n * K + k] = h;
  dl[(size_t)n * K + k] = bf16_rne(v - bf16_f(h));
}

// MFMA tile kernel: acc[i] += A * WT(n0[i]) over K, 3-term split.
// A-frag: lane holds A[row=l&15][k0 + (l>>4)*8 + j]; B-frag from transposed
// weights: WT[n0+l&15][k0 + (l>>4)*8 + j] (16B contiguous per lane).
template <int NT, int KT, int LDA>
__device__ __forceinline__ void mm_tiles(fx4 (&acc)[NT], const int (&n0)[NT],
                                         const u16 (&Ah)[16][LDA], const u16 (&Al)[16][LDA],
                                         const u16* __restrict__ WH, const u16* __restrict__ WL,
                                         const int K, const int lc, const int ao) {
  const u16* wh[NT]; const u16* wl[NT];
#pragma unroll
  for (int i = 0; i < NT; ++i) {
    wh[i] = WH + (size_t)(n0[i] + lc) * K + ao;
    wl[i] = WL + (size_t)(n0[i] + lc) * K + ao;
  }
#pragma unroll
  for (int kt = 0; kt < KT; ++kt) {
    const int k0 = kt * 32;
    bhalf8 a_h = *(const bhalf8*)&Ah[lc][k0 + ao];
    bhalf8 a_l = *(const bhalf8*)&Al[lc][k0 + ao];
#pragma unroll
    for (int i = 0; i < NT; ++i) {
      bhalf8 b_h = *(const bhalf8*)(wh[i] + k0);
      bhalf8 b_l = *(const bhalf8*)(wl[i] + k0);
      acc[i] = __builtin_amdgcn_mfma_f32_16x16x32_bf16(a_h, b_h, acc[i], 0, 0, 0);
      acc[i] = __builtin_amdgcn_mfma_f32_16x16x32_bf16(a_l, b_h, acc[i], 0, 0, 0);
      acc[i] = __builtin_amdgcn_mfma_f32_16x16x32_bf16(a_h, b_l, acc[i], 0, 0, 0);
    }
  }
}

__global__ __launch_bounds__(NTHR, 2)
void gru_mfma(const float* __restrict__ frames, const u16* __restrict__ ws,
              const float* __restrict__ b1g, const float* __restrict__ b1c,
              const float* __restrict__ b2g, const float* __restrict__ b2c,
              const float* __restrict__ Wd, const float* __restrict__ bd,
              float* __restrict__ out) {
  __shared__ alignas(16) u16 A1h[16][LD1], A1l[16][LD1];   // [x | h1 / r*h1]
  __shared__ alignas(16) u16 A2h[16][LD2], A2l[16][LD2];   // [h1n | h2 / r2*h2]

  const int tid = threadIdx.x;
  const int w = tid >> 6;          // wave 0..7
  const int l = tid & 63;
  const int lc = l & 15;           // col within 16-tile / A row
  const int lk = l >> 4;           // k-group
  const int ao = lk * 8;
  const int row0 = lk * 4;         // acc rows row0..row0+3
  const int b0 = blockIdx.x * NB;

  const u16* W1gh = ws + oW1g_h; const u16* W1gl = ws + oW1g_l;
  const u16* W1ch = ws + oW1c_h; const u16* W1cl = ws + oW1c_l;
  const u16* W2gh = ws + oW2g_h; const u16* W2gl = ws + oW2g_l;
  const u16* W2ch = ws + oW2c_h; const u16* W2cl = ws + oW2c_l;

  // bias preloads; wave w owns cols w*32..+31 (layer1) and w*16..+15 (layer2)
  const float bg1r0 = b1g[w * 32 + lc],       bg1r1 = b1g[w * 32 + 16 + lc];
  const float bg1u0 = b1g[256 + w * 32 + lc], bg1u1 = b1g[256 + w * 32 + 16 + lc];
  const float bc10  = b1c[w * 32 + lc],       bc11  = b1c[w * 32 + 16 + lc];
  const float bg2r  = b2g[w * 16 + lc],       bg2u  = b2g[128 + w * 16 + lc];
  const float bc2v  = b2c[w * 16 + lc];

  // zero all LDS (h0 = 0)
  for (int i = tid; i < 16 * LD1; i += NTHR) { (&A1h[0][0])[i] = 0; (&A1l[0][0])[i] = 0; }
  for (int i = tid; i < 16 * LD2; i += NTHR) { (&A2h[0][0])[i] = 0; (&A2l[0][0])[i] = 0; }
  __syncthreads();

  const int xb = tid >> 5, xf = tid & 31;
  const float* fptr = frames + (size_t)(b0 + xb) * (Tc * Fc) + xf;

  for (int t = 0; t < Tc; ++t) {
    // ---- stage x_t (hi/lo) ----
    {
      float xv = fptr[t * Fc];
      u16 h = bf16_rne(xv);
      A1h[xb][xf] = h;
      A1l[xb][xf] = bf16_rne(xv - bf16_f(h));
    }
    __syncthreads();  // B1

    // ---- G1: [x|h1] @ W1g, wave cols {w*32, w*32+16} (r), {256+w*32, +16} (u)
    fx4 acc[4] = { {bg1r0, bg1r0, bg1r0, bg1r0}, {bg1r1, bg1r1, bg1r1, bg1r1},
                   {bg1u0, bg1u0, bg1u0, bg1u0}, {bg1u1, bg1u1, bg1u1, bg1u1} };
    const int n0g1[4] = {w * 32, w * 32 + 16, 256 + w * 32, 256 + w * 32 + 16};
    mm_tiles<4, 9, LD1>(acc, n0g1, A1h, A1l, W1gh, W1gl, K1, lc, ao);

    float rr[2][4], uu[2][4];
#pragma unroll
    for (int i = 0; i < 2; ++i)
#pragma unroll
      for (int q = 0; q < 4; ++q) { rr[i][q] = sigm(acc[i][q]); uu[i][q] = sigm(acc[2 + i][q]); }
    __syncthreads();  // B2 (G1 reads of A1 done)

    // r-phase: h1old -> regs, overwrite h-region with r*h1 (owner-exclusive)
    float hold1[2][4];
#pragma unroll
    for (int i = 0; i < 2; ++i)
#pragma unroll
      for (int q = 0; q < 4; ++q) {
        const int row = row0 + q, col = w * 32 + i * 16 + lc;
        const float hv = bf16_f(A1h[row][Fc + col]) + bf16_f(A1l[row][Fc + col]);
        hold1[i][q] = hv;
        const float rh = rr[i][q] * hv;
        const u16 hh = bf16_rne(rh);
        A1h[row][Fc + col] = hh;
        A1l[row][Fc + col] = bf16_rne(rh - bf16_f(hh));
      }
    __syncthreads();  // B3

    // ---- C1: [x|r*h1] @ W1c, wave cols {w*32, w*32+16} ----
    fx4 accc[2] = { {bc10, bc10, bc10, bc10}, {bc11, bc11, bc11, bc11} };
    const int n0c1[2] = {w * 32, w * 32 + 16};
    mm_tiles<2, 9, LD1>(accc, n0c1, A1h, A1l, W1ch, W1cl, K1, lc, ao);

    float hn1[2][4]; u16 hh1[2][4], hl1[2][4];
#pragma unroll
    for (int i = 0; i < 2; ++i)
#pragma unroll
      for (int q = 0; q < 4; ++q) {
        const float c = tanh_(accc[i][q]);
        const float hn = c + uu[i][q] * (hold1[i][q] - c);
        hn1[i][q] = hn;
        hh1[i][q] = bf16_rne(hn);
        hl1[i][q] = bf16_rne(hn - bf16_f(hh1[i][q]));
      }
    __syncthreads();  // B4 (C1 reads of A1 done)
#pragma unroll
    for (int i = 0; i < 2; ++i)
#pragma unroll
      for (int q = 0; q < 4; ++q) {
        const int row = row0 + q, col = w * 32 + i * 16 + lc;
        A1h[row][Fc + col] = hh1[i][q];  A1l[row][Fc + col] = hl1[i][q];   // h1 for t+1
        A2h[row][col] = hh1[i][q];       A2l[row][col] = hl1[i][q];        // layer2 input
      }
    __syncthreads();  // B5

    // ---- G2: [h1n|h2] @ W2g, wave cols {w*16} (r2), {128+w*16} (u2) ----
    fx4 acc2[2] = { {bg2r, bg2r, bg2r, bg2r}, {bg2u, bg2u, bg2u, bg2u} };
    const int n0g2[2] = {w * 16, 128 + w * 16};
    mm_tiles<2, 12, LD2>(acc2, n0g2, A2h, A2l, W2gh, W2gl, K2, lc, ao);

    float rr2[4], uu2[4];
#pragma unroll
    for (int q = 0; q < 4; ++q) { rr2[q] = sigm(acc2[0][q]); uu2[q] = sigm(acc2[1][q]); }
    __syncthreads();  // B6 (G2 reads of A2 done)

    float hold2[4];
#pragma unroll
    for (int q = 0; q < 4; ++q) {
      const int row = row0 + q, col = w * 16 + lc;
      const float hv = bf16_f(A2h[row][U1 + col]) + bf16_f(A2l[row][U1 + col]);
      hold2[q] = hv;
      const float rh = rr2[q] * hv;
      const u16 hh = bf16_rne(rh);
      A2h[row][U1 + col] = hh;
      A2l[row][U1 + col] = bf16_rne(rh - bf16_f(hh));
    }
    __syncthreads();  // B7

    // ---- C2: [h1n|r2*h2] @ W2c, wave col {w*16} ----
    fx4 acc3[1] = { {bc2v, bc2v, bc2v, bc2v} };
    const int n0c2[1] = {w * 16};
    mm_tiles<1, 12, LD2>(acc3, n0c2, A2h, A2l, W2ch, W2cl, K2, lc, ao);
    __syncthreads();  // B8 (C2 reads of A2 done)
#pragma unroll
    for (int q = 0; q < 4; ++q) {
      const int row = row0 + q, col = w * 16 + lc;
      const float c = tanh_(acc3[0][q]);
      const float hn = c + uu2[q] * (hold2[q] - c);
      const u16 hh = bf16_rne(hn);
      A2h[row][U1 + col] = hh;                      // h2 for t+1 (and final out)
      A2l[row][U1 + col] = bf16_rne(hn - bf16_f(hh));
    }
    __syncthreads();  // loop barrier (h2n visible for next G2 / dense)
  }

  // ---- dense: out[b][o] = bd[o] + h2[b] . Wd[:,o] ----
  {
    const int o = tid & 31, b = tid >> 5;
    float acc = bd[o];
    for (int c = 0; c < U2; ++c) {
      const float hv = bf16_f(A2h[b][U1 + c]) + bf16_f(A2l[b][U1 + c]);
      acc = fmaf(hv, Wd[c * Fc + o], acc);
    }
    out[(size_t)(b0 + b) * Fc + o] = acc;
  }
}

extern "C" void kernel_launch(void* const* d_in, const int* in_sizes, int n_in,
                              void* d_out, int out_size, void* d_ws, size_t ws_size,
                              hipStream_t stream) {
  const float* frames = (const float*)d_in[0];
  const float* W1g = (const float*)d_in[1];
  const float* b1g = (const float*)d_in[2];
  const float* W1c = (const float*)d_in[3];
  const float* b1c = (const float*)d_in[4];
  const float* W2g = (const float*)d_in[5];
  const float* b2g = (const float*)d_in[6];
  const float* W2c = (const float*)d_in[7];
  const float* b2c = (const float*)d_in[8];
  const float* Wd  = (const float*)d_in[9];
  const float* bd  = (const float*)d_in[10];
  u16* ws = (u16*)d_ws;
  float* outp = (float*)d_out;

  const int prep_elems = WTOT / 2;  // one thread writes one (hi,lo) pair
  hipLaunchKernelGGL(prep_weights, dim3((prep_elems + 255) / 256), dim3(256), 0, stream,
                     W1g, W1c, W2g, W2c, ws);
  hipLaunchKernelGGL(gru_mfma, dim3(Bc / NB), dim3(NTHR), 0, stream,
                     frames, ws, b1g, b1c, b2g, b2c, Wd, bd, outp);
}

// Round 3
// 1471.743 us; speedup vs baseline: 3.6469x; 3.2241x over previous
//
#include <hip/hip_runtime.h>

// 2-layer GRU (TF GRUCell) + dense via bf16 MFMA.
// W: single bf16 (transposed, K-contiguous). A (x,h): 2-term bf16 split
// (Ahi+Alo) -> A*W ~= AhiW + AloW, error ~ bf16(W) quantization only.
// One block = 16 batches (one MFMA M-tile) for the whole T loop; weight
// B-fragments register-double-buffered across the K loop.

typedef unsigned short u16;
typedef __attribute__((ext_vector_type(8))) short bhalf8;   // 8 bf16 (4 VGPRs)
typedef __attribute__((ext_vector_type(4))) float fx4;

constexpr int Bc = 4096, Tc = 64, Fc = 32, U1 = 256, U2 = 128;
constexpr int K1 = Fc + U1;   // 288
constexpr int K2 = U1 + U2;   // 384
constexpr int NB = 16, NTHR = 512;
constexpr int LD1 = K1 + 8;   // 296 u16 rows (592B, 16B-aligned)
constexpr int LD2 = K2 + 8;   // 392 u16 rows (784B)

// d_ws layout (u16 offsets): transposed bf16 weights (hi only).
constexpr int nW1g = K1 * 512, nW1c = K1 * 256, nW2g = K2 * 256, nW2c = K2 * 128;
constexpr int oW1g = 0;
constexpr int oW1c = oW1g + nW1g;
constexpr int oW2g = oW1c + nW1c;
constexpr int oW2c = oW2g + nW2g;
constexpr int WTOT = oW2c + nW2c;   // 368640 u16 = 737 KB

__device__ __forceinline__ u16 bf16_rne(float x) {
  unsigned u = __float_as_uint(x);
  return (u16)((u + 0x7fffu + ((u >> 16) & 1u)) >> 16);
}
__device__ __forceinline__ float bf16_f(u16 h) {
  return __uint_as_float(((unsigned)h) << 16);
}
__device__ __forceinline__ float sigm(float x) { return 1.0f / (1.0f + __expf(-x)); }
__device__ __forceinline__ float tanh_(float x) {
  x = fminf(fmaxf(x, -15.0f), 15.0f);
  const float s = __expf(2.0f * x);
  return (s - 1.0f) / (s + 1.0f);
}

// ---- prep: W[K][N] fp32 -> WT[N][K] bf16 ----
__global__ void prep_weights(const float* __restrict__ W1g, const float* __restrict__ W1c,
                             const float* __restrict__ W2g, const float* __restrict__ W2c,
                             u16* __restrict__ ws) {
  int j = blockIdx.x * 256 + threadIdx.x;
  if (j >= WTOT) return;
  const float* src; u16* dst; int K, N, jj;
  if (j < nW1g)                    { src = W1g; K = K1; N = 512; jj = j;                      dst = ws + oW1g; }
  else if (j < nW1g + nW1c)        { src = W1c; K = K1; N = 256; jj = j - nW1g;               dst = ws + oW1c; }
  else if (j < nW1g + nW1c + nW2g) { src = W2g; K = K2; N = 256; jj = j - nW1g - nW1c;        dst = ws + oW2g; }
  else                             { src = W2c; K = K2; N = 128; jj = j - nW1g - nW1c - nW2g; dst = ws + oW2c; }
  int n = jj / K, k = jj - n * K;
  dst[(size_t)n * K + k] = bf16_rne(src[(size_t)k * N + n]);
}

// acc[i] += [Ahi+Alo] * WT(cols n0[i]..+15) over K. B-frags double-buffered.
template <int NT, int KT, int LDA>
__device__ __forceinline__ void mm_tiles(fx4 (&acc)[NT], const int (&n0)[NT],
                                         const u16 (&Ah)[16][LDA], const u16 (&Al)[16][LDA],
                                         const u16* __restrict__ WH,
                                         const int K, const int lc, const int ao) {
  const u16* wp[NT];
#pragma unroll
  for (int i = 0; i < NT; ++i) wp[i] = WH + (size_t)(n0[i] + lc) * K + ao;
  bhalf8 bc[NT], bn[NT];
#pragma unroll
  for (int i = 0; i < NT; ++i) bc[i] = *(const bhalf8*)(wp[i]);
#pragma unroll
  for (int kt = 0; kt < KT; ++kt) {
    const int k0 = kt * 32;
    if (kt + 1 < KT) {
#pragma unroll
      for (int i = 0; i < NT; ++i) bn[i] = *(const bhalf8*)(wp[i] + k0 + 32);
    }
    const bhalf8 a_h = *(const bhalf8*)&Ah[lc][k0 + ao];
    const bhalf8 a_l = *(const bhalf8*)&Al[lc][k0 + ao];
#pragma unroll
    for (int i = 0; i < NT; ++i) {
      acc[i] = __builtin_amdgcn_mfma_f32_16x16x32_bf16(a_h, bc[i], acc[i], 0, 0, 0);
      acc[i] = __builtin_amdgcn_mfma_f32_16x16x32_bf16(a_l, bc[i], acc[i], 0, 0, 0);
    }
#pragma unroll
    for (int i = 0; i < NT; ++i) bc[i] = bn[i];
  }
}

__global__ __launch_bounds__(NTHR, 2)
void gru_mfma(const float* __restrict__ frames, const u16* __restrict__ ws,
              const float* __restrict__ b1g, const float* __restrict__ b1c,
              const float* __restrict__ b2g, const float* __restrict__ b2c,
              const float* __restrict__ Wd, const float* __restrict__ bd,
              float* __restrict__ out) {
  __shared__ alignas(16) u16 A1h[16][LD1], A1l[16][LD1];   // [x | h1 / r*h1]
  __shared__ alignas(16) u16 A2h[16][LD2], A2l[16][LD2];   // [h1n | h2 / r2*h2]

  const int tid = threadIdx.x;
  const int w = tid >> 6;          // wave 0..7
  const int l = tid & 63;
  const int lc = l & 15;           // col-in-tile / A row
  const int lk = l >> 4;           // k-group
  const int ao = lk * 8;
  const int row0 = lk * 4;         // acc rows row0..row0+3
  const int b0 = blockIdx.x * NB;

  const u16* W1gh = ws + oW1g;
  const u16* W1ch = ws + oW1c;
  const u16* W2gh = ws + oW2g;
  const u16* W2ch = ws + oW2c;

  const float bg1r0 = b1g[w * 32 + lc],       bg1r1 = b1g[w * 32 + 16 + lc];
  const float bg1u0 = b1g[256 + w * 32 + lc], bg1u1 = b1g[256 + w * 32 + 16 + lc];
  const float bc10  = b1c[w * 32 + lc],       bc11  = b1c[w * 32 + 16 + lc];
  const float bg2r  = b2g[w * 16 + lc],       bg2u  = b2g[128 + w * 16 + lc];
  const float bc2v  = b2c[w * 16 + lc];

  for (int i = tid; i < 16 * LD1; i += NTHR) { (&A1h[0][0])[i] = 0; (&A1l[0][0])[i] = 0; }
  for (int i = tid; i < 16 * LD2; i += NTHR) { (&A2h[0][0])[i] = 0; (&A2l[0][0])[i] = 0; }
  __syncthreads();

  const int xb = tid >> 5, xf = tid & 31;
  const float* fptr = frames + (size_t)(b0 + xb) * (Tc * Fc) + xf;

  for (int t = 0; t < Tc; ++t) {
    // ---- stage x_t (hi/lo) ----
    {
      float xv = fptr[t * Fc];
      u16 h = bf16_rne(xv);
      A1h[xb][xf] = h;
      A1l[xb][xf] = bf16_rne(xv - bf16_f(h));
    }
    __syncthreads();  // B1

    // ---- G1: [x|h1] @ W1g, wave cols {w*32, +16} (r), {256+w*32, +16} (u)
    fx4 acc[4] = { {bg1r0, bg1r0, bg1r0, bg1r0}, {bg1r1, bg1r1, bg1r1, bg1r1},
                   {bg1u0, bg1u0, bg1u0, bg1u0}, {bg1u1, bg1u1, bg1u1, bg1u1} };
    const int n0g1[4] = {w * 32, w * 32 + 16, 256 + w * 32, 256 + w * 32 + 16};
    mm_tiles<4, 9, LD1>(acc, n0g1, A1h, A1l, W1gh, K1, lc, ao);

    float rr[2][4], uu[2][4];
#pragma unroll
    for (int i = 0; i < 2; ++i)
#pragma unroll
      for (int q = 0; q < 4; ++q) { rr[i][q] = sigm(acc[i][q]); uu[i][q] = sigm(acc[2 + i][q]); }
    __syncthreads();  // B2 (G1 reads of A1 done)

    float hold1[2][4];
#pragma unroll
    for (int i = 0; i < 2; ++i)
#pragma unroll
      for (int q = 0; q < 4; ++q) {
        const int row = row0 + q, col = w * 32 + i * 16 + lc;
        const float hv = bf16_f(A1h[row][Fc + col]) + bf16_f(A1l[row][Fc + col]);
        hold1[i][q] = hv;
        const float rh = rr[i][q] * hv;
        const u16 hh = bf16_rne(rh);
        A1h[row][Fc + col] = hh;
        A1l[row][Fc + col] = bf16_rne(rh - bf16_f(hh));
      }
    __syncthreads();  // B3

    // ---- C1: [x|r*h1] @ W1c, wave cols {w*32, +16} ----
    fx4 accc[2] = { {bc10, bc10, bc10, bc10}, {bc11, bc11, bc11, bc11} };
    const int n0c1[2] = {w * 32, w * 32 + 16};
    mm_tiles<2, 9, LD1>(accc, n0c1, A1h, A1l, W1ch, K1, lc, ao);

    float hn1[2][4]; u16 hh1[2][4], hl1[2][4];
#pragma unroll
    for (int i = 0; i < 2; ++i)
#pragma unroll
      for (int q = 0; q < 4; ++q) {
        const float c = tanh_(accc[i][q]);
        const float hn = c + uu[i][q] * (hold1[i][q] - c);
        hh1[i][q] = bf16_rne(hn);
        hl1[i][q] = bf16_rne(hn - bf16_f(hh1[i][q]));
      }
    __syncthreads();  // B4 (C1 reads of A1 done)
#pragma unroll
    for (int i = 0; i < 2; ++i)
#pragma unroll
      for (int q = 0; q < 4; ++q) {
        const int row = row0 + q, col = w * 32 + i * 16 + lc;
        A1h[row][Fc + col] = hh1[i][q];  A1l[row][Fc + col] = hl1[i][q];   // h1 for t+1
        A2h[row][col] = hh1[i][q];       A2l[row][col] = hl1[i][q];        // layer2 input
      }
    __syncthreads();  // B5

    // ---- G2: [h1n|h2] @ W2g, wave cols {w*16} (r2), {128+w*16} (u2) ----
    fx4 acc2[2] = { {bg2r, bg2r, bg2r, bg2r}, {bg2u, bg2u, bg2u, bg2u} };
    const int n0g2[2] = {w * 16, 128 + w * 16};
    mm_tiles<2, 12, LD2>(acc2, n0g2, A2h, A2l, W2gh, K2, lc, ao);

    float rr2[4], uu2[4];
#pragma unroll
    for (int q = 0; q < 4; ++q) { rr2[q] = sigm(acc2[0][q]); uu2[q] = sigm(acc2[1][q]); }
    __syncthreads();  // B6 (G2 reads of A2 done)

    float hold2[4];
#pragma unroll
    for (int q = 0; q < 4; ++q) {
      const int row = row0 + q, col = w * 16 + lc;
      const float hv = bf16_f(A2h[row][U1 + col]) + bf16_f(A2l[row][U1 + col]);
      hold2[q] = hv;
      const float rh = rr2[q] * hv;
      const u16 hh = bf16_rne(rh);
      A2h[row][U1 + col] = hh;
      A2l[row][U1 + col] = bf16_rne(rh - bf16_f(hh));
    }
    __syncthreads();  // B7

    // ---- C2: [h1n|r2*h2] @ W2c, wave col {w*16} ----
    fx4 acc3[1] = { {bc2v, bc2v, bc2v, bc2v} };
    const int n0c2[1] = {w * 16};
    mm_tiles<1, 12, LD2>(acc3, n0c2, A2h, A2l, W2ch, K2, lc, ao);
    __syncthreads();  // B8 (C2 reads of A2 done)
#pragma unroll
    for (int q = 0; q < 4; ++q) {
      const int row = row0 + q, col = w * 16 + lc;
      const float c = tanh_(acc3[0][q]);
      const float hn = c + uu2[q] * (hold2[q] - c);
      const u16 hh = bf16_rne(hn);
      A2h[row][U1 + col] = hh;                      // h2 for t+1 (and final out)
      A2l[row][U1 + col] = bf16_rne(hn - bf16_f(hh));
    }
    __syncthreads();  // loop barrier
  }

  // ---- dense: out[b][o] = bd[o] + h2[b] . Wd[:,o] ----
  {
    const int o = tid & 31, b = tid >> 5;
    float acc = bd[o];
    for (int c = 0; c < U2; ++c) {
      const float hv = bf16_f(A2h[b][U1 + c]) + bf16_f(A2l[b][U1 + c]);
      acc = fmaf(hv, Wd[c * Fc + o], acc);
    }
    out[(size_t)(b0 + b) * Fc + o] = acc;
  }
}

extern "C" void kernel_launch(void* const* d_in, const int* in_sizes, int n_in,
                              void* d_out, int out_size, void* d_ws, size_t ws_size,
                              hipStream_t stream) {
  const float* frames = (const float*)d_in[0];
  const float* W1g = (const float*)d_in[1];
  const float* b1g = (const float*)d_in[2];
  const float* W1c = (const float*)d_in[3];
  const float* b1c = (const float*)d_in[4];
  const float* W2g = (const float*)d_in[5];
  const float* b2g = (const float*)d_in[6];
  const float* W2c = (const float*)d_in[7];
  const float* b2c = (const float*)d_in[8];
  const float* Wd  = (const float*)d_in[9];
  const float* bd  = (const float*)d_in[10];
  u16* ws = (u16*)d_ws;
  float* outp = (float*)d_out;

  hipLaunchKernelGGL(prep_weights, dim3((WTOT + 255) / 256), dim3(256), 0, stream,
                     W1g, W1c, W2g, W2c, ws);
  hipLaunchKernelGGL(gru_mfma, dim3(Bc / NB), dim3(NTHR), 0, stream,
                     frames, ws, b1g, b1c, b2g, b2c, Wd, bd, outp);
}

// Round 4
// 1416.148 us; speedup vs baseline: 3.7900x; 1.0393x over previous
//
#include <hip/hip_runtime.h>

// 2-layer GRU (TF GRUCell) + dense via bf16 MFMA.
// W: single bf16 (transposed, K-contiguous). A (x,h): 2-term bf16 split.
// R4: depth-D register prefetch pipeline on the weight B-fragments
// (static addresses -> D*NT loads in flight per wave), x_t prefetch,
// hold-reads hoisted above barriers.

typedef unsigned short u16;
typedef __attribute__((ext_vector_type(8))) short bhalf8;   // 8 bf16 (4 VGPRs)
typedef __attribute__((ext_vector_type(4))) float fx4;

constexpr int Bc = 4096, Tc = 64, Fc = 32, U1 = 256, U2 = 128;
constexpr int K1 = Fc + U1;   // 288
constexpr int K2 = U1 + U2;   // 384
constexpr int NB = 16, NTHR = 512;
constexpr int LD1 = K1 + 8;   // 296 u16 rows
constexpr int LD2 = K2 + 8;   // 392 u16 rows

// d_ws layout (u16 offsets): transposed bf16 weights.
constexpr int nW1g = K1 * 512, nW1c = K1 * 256, nW2g = K2 * 256, nW2c = K2 * 128;
constexpr int oW1g = 0;
constexpr int oW1c = oW1g + nW1g;
constexpr int oW2g = oW1c + nW1c;
constexpr int oW2c = oW2g + nW2g;
constexpr int WTOT = oW2c + nW2c;   // 368640 u16 = 737 KB

__device__ __forceinline__ u16 bf16_rne(float x) {
  unsigned u = __float_as_uint(x);
  return (u16)((u + 0x7fffu + ((u >> 16) & 1u)) >> 16);
}
__device__ __forceinline__ float bf16_f(u16 h) {
  return __uint_as_float(((unsigned)h) << 16);
}
__device__ __forceinline__ float sigm(float x) { return 1.0f / (1.0f + __expf(-x)); }
__device__ __forceinline__ float tanh_(float x) {
  x = fminf(fmaxf(x, -15.0f), 15.0f);
  const float s = __expf(2.0f * x);
  return (s - 1.0f) / (s + 1.0f);
}

// ---- prep: W[K][N] fp32 -> WT[N][K] bf16 ----
__global__ void prep_weights(const float* __restrict__ W1g, const float* __restrict__ W1c,
                             const float* __restrict__ W2g, const float* __restrict__ W2c,
                             u16* __restrict__ ws) {
  int j = blockIdx.x * 256 + threadIdx.x;
  if (j >= WTOT) return;
  const float* src; u16* dst; int K, N, jj;
  if (j < nW1g)                    { src = W1g; K = K1; N = 512; jj = j;                      dst = ws + oW1g; }
  else if (j < nW1g + nW1c)        { src = W1c; K = K1; N = 256; jj = j - nW1g;               dst = ws + oW1c; }
  else if (j < nW1g + nW1c + nW2g) { src = W2g; K = K2; N = 256; jj = j - nW1g - nW1c;        dst = ws + oW2g; }
  else                             { src = W2c; K = K2; N = 128; jj = j - nW1g - nW1c - nW2g; dst = ws + oW2c; }
  int n = jj / K, k = jj - n * K;
  dst[(size_t)n * K + k] = bf16_rne(src[(size_t)k * N + n]);
}

// acc[i] += [Ahi+Alo] * WT(cols n0[i]..+15) over K.
// Depth-D rolling register buffer of B-fragments: D*NT loads in flight.
template <int NT, int KT, int D, int LDA>
__device__ __forceinline__ void mm_tiles(fx4 (&acc)[NT], const int (&n0)[NT],
                                         const u16 (&Ah)[16][LDA], const u16 (&Al)[16][LDA],
                                         const u16* __restrict__ WH,
                                         const int K, const int lc, const int ao) {
  const u16* wp[NT];
#pragma unroll
  for (int i = 0; i < NT; ++i) wp[i] = WH + (size_t)(n0[i] + lc) * K + ao;
  bhalf8 bb[D][NT];
#pragma unroll
  for (int d = 0; d < D; ++d) {
    if (d < KT) {
#pragma unroll
      for (int i = 0; i < NT; ++i) bb[d][i] = *(const bhalf8*)(wp[i] + d * 32);
    }
  }
#pragma unroll
  for (int kt = 0; kt < KT; ++kt) {
    const int k0 = kt * 32;
    const bhalf8 a_h = *(const bhalf8*)&Ah[lc][k0 + ao];
    const bhalf8 a_l = *(const bhalf8*)&Al[lc][k0 + ao];
#pragma unroll
    for (int i = 0; i < NT; ++i) {
      acc[i] = __builtin_amdgcn_mfma_f32_16x16x32_bf16(a_h, bb[kt % D][i], acc[i], 0, 0, 0);
      acc[i] = __builtin_amdgcn_mfma_f32_16x16x32_bf16(a_l, bb[kt % D][i], acc[i], 0, 0, 0);
    }
    if (kt + D < KT) {
#pragma unroll
      for (int i = 0; i < NT; ++i) bb[kt % D][i] = *(const bhalf8*)(wp[i] + (kt + D) * 32);
    }
  }
}

__global__ __launch_bounds__(NTHR, 2)
void gru_mfma(const float* __restrict__ frames, const u16* __restrict__ ws,
              const float* __restrict__ b1g, const float* __restrict__ b1c,
              const float* __restrict__ b2g, const float* __restrict__ b2c,
              const float* __restrict__ Wd, const float* __restrict__ bd,
              float* __restrict__ out) {
  __shared__ alignas(16) u16 A1h[16][LD1], A1l[16][LD1];   // [x | h1 / r*h1]
  __shared__ alignas(16) u16 A2h[16][LD2], A2l[16][LD2];   // [h1n | h2 / r2*h2]

  const int tid = threadIdx.x;
  const int w = tid >> 6;          // wave 0..7
  const int l = tid & 63;
  const int lc = l & 15;           // col-in-tile / A row
  const int lk = l >> 4;           // k-group
  const int ao = lk * 8;
  const int row0 = lk * 4;         // acc rows row0..row0+3
  const int b0 = blockIdx.x * NB;

  const u16* W1gh = ws + oW1g;
  const u16* W1ch = ws + oW1c;
  const u16* W2gh = ws + oW2g;
  const u16* W2ch = ws + oW2c;

  const float bg1r0 = b1g[w * 32 + lc],       bg1r1 = b1g[w * 32 + 16 + lc];
  const float bg1u0 = b1g[256 + w * 32 + lc], bg1u1 = b1g[256 + w * 32 + 16 + lc];
  const float bc10  = b1c[w * 32 + lc],       bc11  = b1c[w * 32 + 16 + lc];
  const float bg2r  = b2g[w * 16 + lc],       bg2u  = b2g[128 + w * 16 + lc];
  const float bc2v  = b2c[w * 16 + lc];

  for (int i = tid; i < 16 * LD1; i += NTHR) { (&A1h[0][0])[i] = 0; (&A1l[0][0])[i] = 0; }
  for (int i = tid; i < 16 * LD2; i += NTHR) { (&A2h[0][0])[i] = 0; (&A2l[0][0])[i] = 0; }
  __syncthreads();

  const int xb = tid >> 5, xf = tid & 31;
  const float* fptr = frames + (size_t)(b0 + xb) * (Tc * Fc) + xf;

  float xcur = fptr[0];

  for (int t = 0; t < Tc; ++t) {
    // prefetch next step's x while this step computes
    const float xnxt = (t + 1 < Tc) ? fptr[(t + 1) * Fc] : 0.0f;

    // ---- stage x_t (hi/lo) ----
    {
      const u16 h = bf16_rne(xcur);
      A1h[xb][xf] = h;
      A1l[xb][xf] = bf16_rne(xcur - bf16_f(h));
    }
    __syncthreads();  // B1

    // ---- G1: [x|h1] @ W1g, wave cols {w*32, +16} (r), {256+w*32, +16} (u)
    fx4 acc[4] = { {bg1r0, bg1r0, bg1r0, bg1r0}, {bg1r1, bg1r1, bg1r1, bg1r1},
                   {bg1u0, bg1u0, bg1u0, bg1u0}, {bg1u1, bg1u1, bg1u1, bg1u1} };
    const int n0g1[4] = {w * 32, w * 32 + 16, 256 + w * 32, 256 + w * 32 + 16};
    mm_tiles<4, 9, 4, LD1>(acc, n0g1, A1h, A1l, W1gh, K1, lc, ao);

    // hold1 read hoisted above B2: region is stable until post-B2 writes
    float hold1[2][4];
#pragma unroll
    for (int i = 0; i < 2; ++i)
#pragma unroll
      for (int q = 0; q < 4; ++q) {
        const int row = row0 + q, col = w * 32 + i * 16 + lc;
        hold1[i][q] = bf16_f(A1h[row][Fc + col]) + bf16_f(A1l[row][Fc + col]);
      }

    float rr[2][4], uu[2][4];
#pragma unroll
    for (int i = 0; i < 2; ++i)
#pragma unroll
      for (int q = 0; q < 4; ++q) { rr[i][q] = sigm(acc[i][q]); uu[i][q] = sigm(acc[2 + i][q]); }
    __syncthreads();  // B2 (G1 reads of A1 done)

#pragma unroll
    for (int i = 0; i < 2; ++i)
#pragma unroll
      for (int q = 0; q < 4; ++q) {
        const int row = row0 + q, col = w * 32 + i * 16 + lc;
        const float rh = rr[i][q] * hold1[i][q];
        const u16 hh = bf16_rne(rh);
        A1h[row][Fc + col] = hh;
        A1l[row][Fc + col] = bf16_rne(rh - bf16_f(hh));
      }
    __syncthreads();  // B3

    // ---- C1: [x|r*h1] @ W1c, wave cols {w*32, +16} ----
    fx4 accc[2] = { {bc10, bc10, bc10, bc10}, {bc11, bc11, bc11, bc11} };
    const int n0c1[2] = {w * 32, w * 32 + 16};
    mm_tiles<2, 9, 6, LD1>(accc, n0c1, A1h, A1l, W1ch, K1, lc, ao);

    float hn1[2][4]; u16 hh1[2][4], hl1[2][4];
#pragma unroll
    for (int i = 0; i < 2; ++i)
#pragma unroll
      for (int q = 0; q < 4; ++q) {
        const float c = tanh_(accc[i][q]);
        const float hn = c + uu[i][q] * (hold1[i][q] - c);
        hh1[i][q] = bf16_rne(hn);
        hl1[i][q] = bf16_rne(hn - bf16_f(hh1[i][q]));
      }
    __syncthreads();  // B4 (C1 reads of A1 done)
#pragma unroll
    for (int i = 0; i < 2; ++i)
#pragma unroll
      for (int q = 0; q < 4; ++q) {
        const int row = row0 + q, col = w * 32 + i * 16 + lc;
        A1h[row][Fc + col] = hh1[i][q];  A1l[row][Fc + col] = hl1[i][q];   // h1 for t+1
        A2h[row][col] = hh1[i][q];       A2l[row][col] = hl1[i][q];        // layer2 input
      }
    __syncthreads();  // B5

    // ---- G2: [h1n|h2] @ W2g, wave cols {w*16} (r2), {128+w*16} (u2) ----
    fx4 acc2[2] = { {bg2r, bg2r, bg2r, bg2r}, {bg2u, bg2u, bg2u, bg2u} };
    const int n0g2[2] = {w * 16, 128 + w * 16};
    mm_tiles<2, 12, 6, LD2>(acc2, n0g2, A2h, A2l, W2gh, K2, lc, ao);

    // hold2 hoisted above B6
    float hold2[4];
#pragma unroll
    for (int q = 0; q < 4; ++q) {
      const int row = row0 + q, col = w * 16 + lc;
      hold2[q] = bf16_f(A2h[row][U1 + col]) + bf16_f(A2l[row][U1 + col]);
    }

    float rr2[4], uu2[4];
#pragma unroll
    for (int q = 0; q < 4; ++q) { rr2[q] = sigm(acc2[0][q]); uu2[q] = sigm(acc2[1][q]); }
    __syncthreads();  // B6 (G2 reads of A2 done)

#pragma unroll
    for (int q = 0; q < 4; ++q) {
      const int row = row0 + q, col = w * 16 + lc;
      const float rh = rr2[q] * hold2[q];
      const u16 hh = bf16_rne(rh);
      A2h[row][U1 + col] = hh;
      A2l[row][U1 + col] = bf16_rne(rh - bf16_f(hh));
    }
    __syncthreads();  // B7

    // ---- C2: [h1n|r2*h2] @ W2c, wave col {w*16} ----
    fx4 acc3[1] = { {bc2v, bc2v, bc2v, bc2v} };
    const int n0c2[1] = {w * 16};
    mm_tiles<1, 12, 8, LD2>(acc3, n0c2, A2h, A2l, W2ch, K2, lc, ao);
    __syncthreads();  // B8 (C2 reads of A2 done)
#pragma unroll
    for (int q = 0; q < 4; ++q) {
      const int row = row0 + q, col = w * 16 + lc;
      const float c = tanh_(acc3[0][q]);
      const float hn = c + uu2[q] * (hold2[q] - c);
      const u16 hh = bf16_rne(hn);
      A2h[row][U1 + col] = hh;                      // h2 for t+1 (and final out)
      A2l[row][U1 + col] = bf16_rne(hn - bf16_f(hh));
    }
    __syncthreads();  // loop barrier

    xcur = xnxt;
  }

  // ---- dense: out[b][o] = bd[o] + h2[b] . Wd[:,o] ----
  {
    const int o = tid & 31, b = tid >> 5;
    float acc = bd[o];
    for (int c = 0; c < U2; ++c) {
      const float hv = bf16_f(A2h[b][U1 + c]) + bf16_f(A2l[b][U1 + c]);
      acc = fmaf(hv, Wd[c * Fc + o], acc);
    }
    out[(size_t)(b0 + b) * Fc + o] = acc;
  }
}

extern "C" void kernel_launch(void* const* d_in, const int* in_sizes, int n_in,
                              void* d_out, int out_size, void* d_ws, size_t ws_size,
                              hipStream_t stream) {
  const float* frames = (const float*)d_in[0];
  const float* W1g = (const float*)d_in[1];
  const float* b1g = (const float*)d_in[2];
  const float* W1c = (const float*)d_in[3];
  const float* b1c = (const float*)d_in[4];
  const float* W2g = (const float*)d_in[5];
  const float* b2g = (const float*)d_in[6];
  const float* W2c = (const float*)d_in[7];
  const float* b2c = (const float*)d_in[8];
  const float* Wd  = (const float*)d_in[9];
  const float* bd  = (const float*)d_in[10];
  u16* ws = (u16*)d_ws;
  float* outp = (float*)d_out;

  hipLaunchKernelGGL(prep_weights, dim3((WTOT + 255) / 256), dim3(256), 0, stream,
                     W1g, W1c, W2g, W2c, ws);
  hipLaunchKernelGGL(gru_mfma, dim3(Bc / NB), dim3(NTHR), 0, stream,
                     frames, ws, b1g, b1c, b2g, b2c, Wd, bd, outp);
}

// Round 5
// 881.098 us; speedup vs baseline: 6.0916x; 1.6073x over previous
//
#include <hip/hip_runtime.h>

// 2-layer GRU (TF GRUCell) + dense via bf16 MFMA.
// R5: raw s_barrier + lgkmcnt(0) only (no vmcnt drain at barriers) so the
// weight B-fragment stream stays in flight across all intra-step barriers;
// cross-phase prefetch (next phase's fragments issued right after current
// phase's MFMAs); step-invariant weight pointers hoisted out of the t-loop;
// dense epilogue vectorized via prep-transposed WdT.

typedef unsigned short u16;
typedef __attribute__((ext_vector_type(8))) short bhalf8;   // 8 bf16 (4 VGPRs)
typedef __attribute__((ext_vector_type(4))) float fx4;

constexpr int Bc = 4096, Tc = 64, Fc = 32, U1 = 256, U2 = 128;
constexpr int K1 = Fc + U1;   // 288
constexpr int K2 = U1 + U2;   // 384
constexpr int NB = 16, NTHR = 512;
constexpr int LD1 = K1 + 8;   // 296 u16 rows
constexpr int LD2 = K2 + 8;   // 392 u16 rows

// d_ws layout: u16 transposed bf16 weights, then fp32 WdT[32][128].
constexpr int nW1g = K1 * 512, nW1c = K1 * 256, nW2g = K2 * 256, nW2c = K2 * 128;
constexpr int oW1g = 0;
constexpr int oW1c = oW1g + nW1g;
constexpr int oW2g = oW1c + nW1c;
constexpr int oW2c = oW2g + nW2g;
constexpr int WTOT = oW2c + nW2c;   // 368640 u16 = 720 KiB (16B-aligned end)
constexpr int nWdT = Fc * U2;       // 4096 floats

// LDS-only barrier: waits DS ops, leaves global loads in flight.
#define LGKM_BARRIER() asm volatile("s_waitcnt lgkmcnt(0)\n\ts_barrier" ::: "memory")

__device__ __forceinline__ u16 bf16_rne(float x) {
  unsigned u = __float_as_uint(x);
  return (u16)((u + 0x7fffu + ((u >> 16) & 1u)) >> 16);
}
__device__ __forceinline__ float bf16_f(u16 h) {
  return __uint_as_float(((unsigned)h) << 16);
}
__device__ __forceinline__ float sigm(float x) { return 1.0f / (1.0f + __expf(-x)); }
__device__ __forceinline__ float tanh_(float x) {
  x = fminf(fmaxf(x, -15.0f), 15.0f);
  const float s = __expf(2.0f * x);
  return (s - 1.0f) / (s + 1.0f);
}

// ---- prep: W[K][N] fp32 -> WT[N][K] bf16; Wd[128][32] -> WdT fp32 ----
__global__ void prep_weights(const float* __restrict__ W1g, const float* __restrict__ W1c,
                             const float* __restrict__ W2g, const float* __restrict__ W2c,
                             const float* __restrict__ Wd, u16* __restrict__ ws) {
  int j = blockIdx.x * 256 + threadIdx.x;
  if (j >= WTOT + nWdT) return;
  if (j >= WTOT) {
    const int jj = j - WTOT;           // jj = o*128 + c
    float* wdT = (float*)(ws + WTOT);
    const int o = jj >> 7, c = jj & 127;
    wdT[jj] = Wd[c * Fc + o];
    return;
  }
  const float* src; u16* dst; int K, N, jj;
  if (j < nW1g)                    { src = W1g; K = K1; N = 512; jj = j;                      dst = ws + oW1g; }
  else if (j < nW1g + nW1c)        { src = W1c; K = K1; N = 256; jj = j - nW1g;               dst = ws + oW1c; }
  else if (j < nW1g + nW1c + nW2g) { src = W2g; K = K2; N = 256; jj = j - nW1g - nW1c;        dst = ws + oW2g; }
  else                             { src = W2c; K = K2; N = 128; jj = j - nW1g - nW1c - nW2g; dst = ws + oW2c; }
  int n = jj / K, k = jj - n * K;
  dst[(size_t)n * K + k] = bf16_rne(src[(size_t)k * N + n]);
}

// Rolling-register weight pipe. Addresses step-invariant; prefetch() refills
// the first D k-groups; mm() consumes KT k-groups, rolling loads kt+D.
template <int NT, int D>
struct Pipe {
  const u16* wp[NT];
  bhalf8 bb[D][NT];
  __device__ __forceinline__ void init(const u16* __restrict__ W, const int* n0,
                                       int K, int lc, int ao) {
#pragma unroll
    for (int i = 0; i < NT; ++i) wp[i] = W + (size_t)(n0[i] + lc) * K + ao;
  }
  __device__ __forceinline__ void prefetch() {
#pragma unroll
    for (int d = 0; d < D; ++d)
#pragma unroll
      for (int i = 0; i < NT; ++i) bb[d][i] = *(const bhalf8*)(wp[i] + d * 32);
  }
  template <int KT, int LDA>
  __device__ __forceinline__ void mm(fx4 (&acc)[NT], const u16 (&Ah)[16][LDA],
                                     const u16 (&Al)[16][LDA], int lc, int ao) {
#pragma unroll
    for (int kt = 0; kt < KT; ++kt) {
      const int k0 = kt * 32;
      const bhalf8 a_h = *(const bhalf8*)&Ah[lc][k0 + ao];
      const bhalf8 a_l = *(const bhalf8*)&Al[lc][k0 + ao];
#pragma unroll
      for (int i = 0; i < NT; ++i) {
        acc[i] = __builtin_amdgcn_mfma_f32_16x16x32_bf16(a_h, bb[kt % D][i], acc[i], 0, 0, 0);
        acc[i] = __builtin_amdgcn_mfma_f32_16x16x32_bf16(a_l, bb[kt % D][i], acc[i], 0, 0, 0);
      }
      if (kt + D < KT) {
#pragma unroll
        for (int i = 0; i < NT; ++i) bb[kt % D][i] = *(const bhalf8*)(wp[i] + (kt + D) * 32);
      }
    }
  }
};

__global__ __launch_bounds__(NTHR, 2)
void gru_mfma(const float* __restrict__ frames, const u16* __restrict__ ws,
              const float* __restrict__ b1g, const float* __restrict__ b1c,
              const float* __restrict__ b2g, const float* __restrict__ b2c,
              const float* __restrict__ bd, float* __restrict__ out) {
  __shared__ alignas(16) u16 A1h[16][LD1], A1l[16][LD1];   // [x | h1 / r*h1]
  __shared__ alignas(16) u16 A2h[16][LD2], A2l[16][LD2];   // [h1n | h2 / r2*h2]

  const int tid = threadIdx.x;
  const int w = tid >> 6;          // wave 0..7
  const int l = tid & 63;
  const int lc = l & 15;           // col-in-tile / A row
  const int lk = l >> 4;           // k-group
  const int ao = lk * 8;
  const int row0 = lk * 4;         // acc rows row0..row0+3
  const int b0 = blockIdx.x * NB;

  const float bg1r0 = b1g[w * 32 + lc],       bg1r1 = b1g[w * 32 + 16 + lc];
  const float bg1u0 = b1g[256 + w * 32 + lc], bg1u1 = b1g[256 + w * 32 + 16 + lc];
  const float bc10  = b1c[w * 32 + lc],       bc11  = b1c[w * 32 + 16 + lc];
  const float bg2r  = b2g[w * 16 + lc],       bg2u  = b2g[128 + w * 16 + lc];
  const float bc2v  = b2c[w * 16 + lc];

  // step-invariant weight pipes
  Pipe<4, 4> pG1;  Pipe<2, 4> pC1;  Pipe<2, 4> pG2;  Pipe<1, 4> pC2;
  const int n0g1[4] = {w * 32, w * 32 + 16, 256 + w * 32, 256 + w * 32 + 16};
  const int n0c1[2] = {w * 32, w * 32 + 16};
  const int n0g2[2] = {w * 16, 128 + w * 16};
  const int n0c2[1] = {w * 16};
  pG1.init(ws + oW1g, n0g1, K1, lc, ao);
  pC1.init(ws + oW1c, n0c1, K1, lc, ao);
  pG2.init(ws + oW2g, n0g2, K2, lc, ao);
  pC2.init(ws + oW2c, n0c2, K2, lc, ao);

  for (int i = tid; i < 16 * LD1; i += NTHR) { (&A1h[0][0])[i] = 0; (&A1l[0][0])[i] = 0; }
  for (int i = tid; i < 16 * LD2; i += NTHR) { (&A2h[0][0])[i] = 0; (&A2l[0][0])[i] = 0; }

  const int xb = tid >> 5, xf = tid & 31;
  const float* fptr = frames + (size_t)(b0 + xb) * (Tc * Fc) + xf;

  // prologue: stage x_0, prefetch G1
  {
    const float x0 = fptr[0];
    const u16 h = bf16_rne(x0);
    A1h[xb][xf] = h;
    A1l[xb][xf] = bf16_rne(x0 - bf16_f(h));
  }
  pG1.prefetch();
  LGKM_BARRIER();   // zero-init + x0 visible

  for (int t = 0; t < Tc; ++t) {
    // x for step t+1, consumed (converted + staged) at the tail of this body
    const float xnxt = (t + 1 < Tc) ? fptr[(t + 1) * Fc] : 0.0f;

    // ---- G1: [x|h1] @ W1g ----
    fx4 acc[4] = { {bg1r0, bg1r0, bg1r0, bg1r0}, {bg1r1, bg1r1, bg1r1, bg1r1},
                   {bg1u0, bg1u0, bg1u0, bg1u0}, {bg1u1, bg1u1, bg1u1, bg1u1} };
    pG1.mm<9, LD1>(acc, A1h, A1l, lc, ao);
    pC1.prefetch();            // C1 weights fly across B2/B3

    float hold1[2][4];         // stable until post-B2 writes
#pragma unroll
    for (int i = 0; i < 2; ++i)
#pragma unroll
      for (int q = 0; q < 4; ++q) {
        const int row = row0 + q, col = w * 32 + i * 16 + lc;
        hold1[i][q] = bf16_f(A1h[row][Fc + col]) + bf16_f(A1l[row][Fc + col]);
      }
    float rr[2][4], uu[2][4];
#pragma unroll
    for (int i = 0; i < 2; ++i)
#pragma unroll
      for (int q = 0; q < 4; ++q) { rr[i][q] = sigm(acc[i][q]); uu[i][q] = sigm(acc[2 + i][q]); }
    LGKM_BARRIER();  // B2: all G1 reads of A1 done

#pragma unroll
    for (int i = 0; i < 2; ++i)
#pragma unroll
      for (int q = 0; q < 4; ++q) {
        const int row = row0 + q, col = w * 32 + i * 16 + lc;
        const float rh = rr[i][q] * hold1[i][q];
        const u16 hh = bf16_rne(rh);
        A1h[row][Fc + col] = hh;
        A1l[row][Fc + col] = bf16_rne(rh - bf16_f(hh));
      }
    LGKM_BARRIER();  // B3: r*h1 visible

    // ---- C1: [x|r*h1] @ W1c ----
    fx4 accc[2] = { {bc10, bc10, bc10, bc10}, {bc11, bc11, bc11, bc11} };
    pC1.mm<9, LD1>(accc, A1h, A1l, lc, ao);
    pG2.prefetch();            // G2 weights fly across B4/B5

    float hn1[2][4]; u16 hh1[2][4], hl1[2][4];
#pragma unroll
    for (int i = 0; i < 2; ++i)
#pragma unroll
      for (int q = 0; q < 4; ++q) {
        const float c = tanh_(accc[i][q]);
        const float hn = c + uu[i][q] * (hold1[i][q] - c);
        hh1[i][q] = bf16_rne(hn);
        hl1[i][q] = bf16_rne(hn - bf16_f(hh1[i][q]));
      }
    LGKM_BARRIER();  // B4: C1 reads of A1 done
#pragma unroll
    for (int i = 0; i < 2; ++i)
#pragma unroll
      for (int q = 0; q < 4; ++q) {
        const int row = row0 + q, col = w * 32 + i * 16 + lc;
        A1h[row][Fc + col] = hh1[i][q];  A1l[row][Fc + col] = hl1[i][q];   // h1 for t+1
        A2h[row][col] = hh1[i][q];       A2l[row][col] = hl1[i][q];        // layer2 input
      }
    LGKM_BARRIER();  // B5: h1n visible

    // ---- G2: [h1n|h2] @ W2g ----
    fx4 acc2[2] = { {bg2r, bg2r, bg2r, bg2r}, {bg2u, bg2u, bg2u, bg2u} };
    pG2.mm<12, LD2>(acc2, A2h, A2l, lc, ao);
    pC2.prefetch();            // C2 weights fly across B6/B7

    float hold2[4];
#pragma unroll
    for (int q = 0; q < 4; ++q) {
      const int row = row0 + q, col = w * 16 + lc;
      hold2[q] = bf16_f(A2h[row][U1 + col]) + bf16_f(A2l[row][U1 + col]);
    }
    float rr2[4], uu2[4];
#pragma unroll
    for (int q = 0; q < 4; ++q) { rr2[q] = sigm(acc2[0][q]); uu2[q] = sigm(acc2[1][q]); }
    LGKM_BARRIER();  // B6: G2 reads of A2 done

#pragma unroll
    for (int q = 0; q < 4; ++q) {
      const int row = row0 + q, col = w * 16 + lc;
      const float rh = rr2[q] * hold2[q];
      const u16 hh = bf16_rne(rh);
      A2h[row][U1 + col] = hh;
      A2l[row][U1 + col] = bf16_rne(rh - bf16_f(hh));
    }
    LGKM_BARRIER();  // B7: r2*h2 visible

    // ---- C2: [h1n|r2*h2] @ W2c ----
    fx4 acc3[1] = { {bc2v, bc2v, bc2v, bc2v} };
    pC2.mm<12, LD2>(acc3, A2h, A2l, lc, ao);
    pG1.prefetch();            // next step's G1 weights fly across tail barriers
    LGKM_BARRIER();  // B8: C2 reads of A2 done

#pragma unroll
    for (int q = 0; q < 4; ++q) {
      const int row = row0 + q, col = w * 16 + lc;
      const float c = tanh_(acc3[0][q]);
      const float hn = c + uu2[q] * (hold2[q] - c);
      const u16 hh = bf16_rne(hn);
      A2h[row][U1 + col] = hh;                      // h2 for t+1 (and final out)
      A2l[row][U1 + col] = bf16_rne(hn - bf16_f(hh));
    }
    // stage x_{t+1} (A1 x-region: last reader was C1, done at B4)
    {
      const u16 h = bf16_rne(xnxt);
      A1h[xb][xf] = h;
      A1l[xb][xf] = bf16_rne(xnxt - bf16_f(h));
    }
    LGKM_BARRIER();  // loop: h2n + x_{t+1} visible
  }

  // ---- dense: out[b][o] = bd[o] + h2[b] . Wd[:,o]  (WdT fp32 in ws) ----
  {
    const float* wdT = (const float*)(ws + WTOT);   // [32][128]
    const int o = tid & 31, b = tid >> 5;
    const float4* wrow = (const float4*)(wdT + o * 128);
    float acc = bd[o];
#pragma unroll 8
    for (int c4 = 0; c4 < 32; ++c4) {
      const float4 wv = wrow[c4];
      const int c = c4 * 4;
      const float h0 = bf16_f(A2h[b][U1 + c + 0]) + bf16_f(A2l[b][U1 + c + 0]);
      const float h1 = bf16_f(A2h[b][U1 + c + 1]) + bf16_f(A2l[b][U1 + c + 1]);
      const float h2 = bf16_f(A2h[b][U1 + c + 2]) + bf16_f(A2l[b][U1 + c + 2]);
      const float h3 = bf16_f(A2h[b][U1 + c + 3]) + bf16_f(A2l[b][U1 + c + 3]);
      acc = fmaf(h0, wv.x, fmaf(h1, wv.y, fmaf(h2, wv.z, fmaf(h3, wv.w, acc))));
    }
    out[(size_t)(b0 + b) * Fc + o] = acc;
  }
}

extern "C" void kernel_launch(void* const* d_in, const int* in_sizes, int n_in,
                              void* d_out, int out_size, void* d_ws, size_t ws_size,
                              hipStream_t stream) {
  const float* frames = (const float*)d_in[0];
  const float* W1g = (const float*)d_in[1];
  const float* b1g = (const float*)d_in[2];
  const float* W1c = (const float*)d_in[3];
  const float* b1c = (const float*)d_in[4];
  const float* W2g = (const float*)d_in[5];
  const float* b2g = (const float*)d_in[6];
  const float* W2c = (const float*)d_in[7];
  const float* b2c = (const float*)d_in[8];
  const float* Wd  = (const float*)d_in[9];
  const float* bd  = (const float*)d_in[10];
  u16* ws = (u16*)d_ws;
  float* outp = (float*)d_out;

  hipLaunchKernelGGL(prep_weights, dim3((WTOT + nWdT + 255) / 256), dim3(256), 0, stream,
                     W1g, W1c, W2g, W2c, Wd, ws);
  hipLaunchKernelGGL(gru_mfma, dim3(Bc / NB), dim3(NTHR), 0, stream,
                     frames, ws, b1g, b1c, b2g, b2c, bd, outp);
}